// Round 8
// baseline (2370.841 us; speedup 1.0000x reference)
//
#include <hip/hip_runtime.h>
#include <hip/hip_bf16.h>

// CustomLSTMModel: emb(32000x300 fp32, pad_idx=0) -> LSTM(300->512, 512 steps, B=256, fp32)
//                  -> FC(512->7, fp32). tokens int32; out fp32 [256,7].
// Internal: bf16 MFMA (RNE), fp32 accum/c/biases/FC. absmax ~1e-3 (R2..R7: 9.8e-4).
//
// R8 changes vs R7 (2.16 ms, LDS-read-bound: 8 waves x full 53KB u-panel = 425 KB
// LDS reads per block-step + 1825 conflict-cyc/step):
//  - 2-D wave tiling (M-pair x K-half): wave (mm,ks) covers M-tiles {2mm,2mm+1}
//    (32 gate rows = 8 units), BOTH N-tiles, K-half ks. Per-wave B-frag reads
//    halve (26 KB); block total 212 KB (was 425). W regs unchanged (104 VGPR).
//  - K-reduction: ks=1 waves write 16 fp32 partials to 16KB LDS scratch (b32
//    lane-indexed = 2-way bank = free), one extra barrier, ks=0 waves merge and
//    do elementwise/pack/store/publish (4 producer flags/block, was 8).
//  - ih K-split stays x-region-aligned (ks0: x-chunks 0..4, ks1: 5..9) so the
//    ih-before-poll overlap is preserved; hh: ks0 h-chunks 0..7, ks1 8..15.
// Carried: no fences (relaxed agent atomics, LLC-coherent); x prefetch into VGPRs
// (R6); per-wave publish after own vmcnt drain (R7); 8 groups x 16 blocks x 512
// thr; 128 blocks -> 1 block/CU; group = bid&7 (XCD round-robin).

typedef unsigned short ushort_t;
typedef unsigned long long u64_t;
typedef __bf16 bf16x8 __attribute__((ext_vector_type(8)));
typedef unsigned short u16x8v __attribute__((ext_vector_type(8)));
typedef float f32x4 __attribute__((ext_vector_type(4)));

#define U_STRIDE 840   // ushorts: 320 (x incl zero pad) + 512 (h) + 8 pad; row = 1680B
#define HOFF 320

__device__ __forceinline__ float sigmoidf_(float x) { return 1.0f / (1.0f + __expf(-x)); }
__device__ __forceinline__ float tanhf_(float x)    { return 1.0f - 2.0f / (__expf(2.0f * x) + 1.0f); }

__device__ __forceinline__ ushort_t f2bf(float f) {   // RNE; inputs finite
    unsigned u = __builtin_bit_cast(unsigned, f);
    unsigned r = (u + 0x7FFFu + ((u >> 16) & 1u)) >> 16;
    return (ushort_t)r;
}
__device__ __forceinline__ float bf2f(ushort_t u) {
    unsigned v = ((unsigned)u) << 16;
    return __builtin_bit_cast(float, v);
}

// LLC-coherent (cache-bypassing) accessors — relaxed agent atomics, no fences.
__device__ __forceinline__ u64_t g_load64(const u64_t* p) {
    return __hip_atomic_load(p, __ATOMIC_RELAXED, __HIP_MEMORY_SCOPE_AGENT);
}
__device__ __forceinline__ void g_store64(u64_t* p, u64_t v) {
    __hip_atomic_store(p, v, __ATOMIC_RELAXED, __HIP_MEMORY_SCOPE_AGENT);
}
__device__ __forceinline__ int g_load_flag(const int* p) {
    return __hip_atomic_load(p, __ATOMIC_RELAXED, __HIP_MEMORY_SCOPE_AGENT);
}
__device__ __forceinline__ void g_store_flag(int* p, int v) {
    __hip_atomic_store(p, v, __ATOMIC_RELAXED, __HIP_MEMORY_SCOPE_AGENT);
}

__global__ __launch_bounds__(512, 2)
void lstm_fused_kernel(const int* __restrict__ tokens,    // [256][512]
                       const float* __restrict__ emb,     // [32000][300]
                       const float* __restrict__ Wih,     // [2048][300]
                       const float* __restrict__ bih,     // [2048]
                       const float* __restrict__ Whh,     // [2048][512]
                       const float* __restrict__ bhh,     // [2048]
                       const float* __restrict__ Wfc,     // [7][512]
                       const float* __restrict__ bfc,     // [7]
                       float* __restrict__ out,           // [256][7]
                       int* __restrict__ flags,           // [512]: 64 per group
                       ushort_t* __restrict__ hbuf)       // [2][256][512] bf16
{
    __shared__ ushort_t u_lds[32 * U_STRIDE];   // 53760 B
    __shared__ float red_scr[4 * 16 * 64];      // 16384 B K-reduction scratch

    const int tid = threadIdx.x;
    const int bid = blockIdx.x;
    const int g   = bid & 7;       // batch group 0..7 (XCD-aligned round-robin)
    const int ib  = bid >> 3;      // block-in-group 0..15 -> unit slice
    const int Bg0 = g * 32;
    const int U0  = ib * 32;       // 32 units per block
    const int lane = tid & 63;
    const int wv   = tid >> 6;     // wave 0..7
    const int mm   = wv >> 1;      // M-pair 0..3: M-tiles {2mm, 2mm+1} = units U0+8mm..+7
    const int ks   = wv & 1;       // K-half
    const int lm   = lane & 15;
    const int q    = lane >> 4;

    // ---- preload A-fragments for 2 M-tiles x K-half, fp32 -> bf16 RNE (once) ----
    bf16x8 aih[5][2];   // [x-chunk][tile]
    bf16x8 ahh[8][2];   // [h-chunk][tile]
#pragma unroll
    for (int ti = 0; ti < 2; ++ti) {
        const int rp   = 32 * mm + 16 * ti + lm;   // row in block's 128 (unit_local*4+gate)
        const int gate = rp & 3;
        const int ul   = rp >> 2;                   // unit_local 0..31
        const int grow = gate * 512 + U0 + ul;      // global gate row
#pragma unroll
        for (int c = 0; c < 5; ++c) {
            u16x8v tmp;
#pragma unroll
            for (int j = 0; j < 8; ++j) {
                int col = 32 * (5 * ks + c) + 8 * q + j;
                tmp[j] = (col < 300) ? f2bf(Wih[grow * 300 + col]) : (ushort_t)0;
            }
            aih[c][ti] = __builtin_bit_cast(bf16x8, tmp);
        }
#pragma unroll
        for (int c = 0; c < 8; ++c) {
            u16x8v tmp;
#pragma unroll
            for (int j = 0; j < 8; ++j) {
                int col = 32 * (8 * ks + c) + 8 * q + j;
                tmp[j] = f2bf(Whh[grow * 512 + col]);
            }
            ahh[c][ti] = __builtin_bit_cast(bf16x8, tmp);
        }
    }

    // ---- per-lane biases: 2 units (one per tile), 4 gates each ----
    float bias[2][4];
#pragma unroll
    for (int ti = 0; ti < 2; ++ti) {
        const int unit = U0 + 8 * mm + 4 * ti + q;
#pragma unroll
        for (int gi = 0; gi < 4; ++gi)
            bias[ti][gi] = bih[gi * 512 + unit] + bhh[gi * 512 + unit];
    }

    // ---- init: zero h parity-0 (h0=0), publish 4 producer flags = 1 ----
    if (tid < 256) {
        int r = tid >> 3;
        int d = tid & 7;
        g_store64((u64_t*)(hbuf + (size_t)(Bg0 + r) * 512 + U0 + 4 * d), 0ull);
    }
    __syncthreads();
    if (tid < 4) g_store_flag(&flags[g * 64 + ib * 4 + tid], 1);

    const int* myflag = &flags[g * 64 + lane];     // poll: 1 flag per lane (64/group)
    int* mypub = &flags[g * 64 + ib * 4 + mm];     // this wave's flag (ks==0 only)

    float cst[2][2] = {{0.f, 0.f}, {0.f, 0.f}};    // c-state per (tile, ntile)

    // ---- x prefetch state (R6/R7): thread covers row xr, elements xln+16k ----
    const int xr  = tid >> 4;
    const int xln = tid & 15;
    const int xb  = Bg0 + xr;
    int tok_cur, tok_nxt;
    float2 xp[10];
    {
        int tk0 = tokens[xb * 512 + 0];
        const float2* s2 = (const float2*)(emb + (size_t)tk0 * 300);
        unsigned int* dstx = (unsigned int*)(u_lds + xr * U_STRIDE);
        const bool tz = (tk0 != 0);
#pragma unroll
        for (int k = 0; k < 10; ++k) {
            int i = xln + 16 * k;
            unsigned int v = 0u;
            if (tz && i < 150) {
                float2 p = s2[i];
                v = (unsigned int)f2bf(p.x) | ((unsigned int)f2bf(p.y) << 16);
            }
            dstx[i] = v;
        }
        tok_cur = tokens[xb * 512 + 1];
        const float2* s2n = (const float2*)(emb + (size_t)tok_cur * 300);
#pragma unroll
        for (int k = 0; k < 10; ++k) {
            int i = xln + 16 * k;
            if (i < 150) xp[k] = s2n[i];
        }
        tok_nxt = tokens[xb * 512 + 2];
    }
    __syncthreads();   // x_0 staged

    for (int t = 0; t < 512; ++t) {
        // ---- 1. ih-MFMAs: 2 tiles x 2 N x 5 x-chunks (K-half ks) ----
        f32x4 acc[2][2] = {{{0,0,0,0},{0,0,0,0}},{{0,0,0,0},{0,0,0,0}}};  // [ti][nt]
        const ushort_t* u0 = u_lds + lm * U_STRIDE + 8 * q;          // batches Bg0+0..15
        const ushort_t* u1 = u_lds + (16 + lm) * U_STRIDE + 8 * q;   // batches Bg0+16..31
#pragma unroll
        for (int c = 0; c < 5; ++c) {
            const int off = 32 * (5 * ks + c);
            bf16x8 b0 = __builtin_bit_cast(bf16x8, *(const u16x8v*)(u0 + off));
            bf16x8 b1 = __builtin_bit_cast(bf16x8, *(const u16x8v*)(u1 + off));
            acc[0][0] = __builtin_amdgcn_mfma_f32_16x16x32_bf16(aih[c][0], b0, acc[0][0], 0, 0, 0);
            acc[1][0] = __builtin_amdgcn_mfma_f32_16x16x32_bf16(aih[c][1], b0, acc[1][0], 0, 0, 0);
            acc[0][1] = __builtin_amdgcn_mfma_f32_16x16x32_bf16(aih[c][0], b1, acc[0][1], 0, 0, 0);
            acc[1][1] = __builtin_amdgcn_mfma_f32_16x16x32_bf16(aih[c][1], b1, acc[1][1], 0, 0, 0);
        }

        // ---- 2. wave 0 polls the 64 group flags (monotonic; poison<0 safe) ----
        if (wv == 0) {
            const int target = t + 1;
            while (true) {
                int v = g_load_flag(myflag);
                if (__all(v >= target)) break;
                __builtin_amdgcn_s_sleep(1);
            }
            asm volatile("" ::: "memory");
        }
        __syncthreads();   // S2a

        // ---- 3. stage h_t via bypassing u64 loads -> LDS ----
        {
            const u64_t* hsrc = (const u64_t*)(hbuf + (size_t)(t & 1) * (256 * 512)
                                               + (size_t)xb * 512);
            u64_t* dsth = (u64_t*)(u_lds + xr * U_STRIDE + HOFF);
            u64_t tmp[8];
#pragma unroll
            for (int k = 0; k < 8; ++k) tmp[k] = g_load64(hsrc + xln + 16 * k);
#pragma unroll
            for (int k = 0; k < 8; ++k) dsth[xln + 16 * k] = tmp[k];
        }
        __syncthreads();   // S2b

        // ---- 4. hh-MFMAs: 2 tiles x 2 N x 8 h-chunks (K-half ks) ----
#pragma unroll
        for (int c = 0; c < 8; ++c) {
            const int off = HOFF + 32 * (8 * ks + c);
            bf16x8 b0 = __builtin_bit_cast(bf16x8, *(const u16x8v*)(u0 + off));
            bf16x8 b1 = __builtin_bit_cast(bf16x8, *(const u16x8v*)(u1 + off));
            acc[0][0] = __builtin_amdgcn_mfma_f32_16x16x32_bf16(ahh[c][0], b0, acc[0][0], 0, 0, 0);
            acc[1][0] = __builtin_amdgcn_mfma_f32_16x16x32_bf16(ahh[c][1], b0, acc[1][0], 0, 0, 0);
            acc[0][1] = __builtin_amdgcn_mfma_f32_16x16x32_bf16(ahh[c][0], b1, acc[0][1], 0, 0, 0);
            acc[1][1] = __builtin_amdgcn_mfma_f32_16x16x32_bf16(ahh[c][1], b1, acc[1][1], 0, 0, 0);
        }

        // ---- 5. K-reduction: ks1 writes partials (b32 lane-indexed = 2-way free) ----
        if (ks == 1) {
            float* dst = red_scr + mm * 1024 + lane;
#pragma unroll
            for (int ti = 0; ti < 2; ++ti)
#pragma unroll
                for (int nt = 0; nt < 2; ++nt)
#pragma unroll
                    for (int cc = 0; cc < 4; ++cc)
                        dst[((ti * 2 + nt) * 4 + cc) * 64] = acc[ti][nt][cc];
        }
        __syncthreads();   // S3: partials visible

        // ---- 6. ks0: merge + elementwise + pack + store + drain + publish ----
        if (ks == 0) {
            const float* src = red_scr + mm * 1024 + lane;
#pragma unroll
            for (int ti = 0; ti < 2; ++ti)
#pragma unroll
                for (int nt = 0; nt < 2; ++nt)
#pragma unroll
                    for (int cc = 0; cc < 4; ++cc)
                        acc[ti][nt][cc] += src[((ti * 2 + nt) * 4 + cc) * 64];

            unsigned p[2][2];
#pragma unroll
            for (int ti = 0; ti < 2; ++ti)
#pragma unroll
                for (int nt = 0; nt < 2; ++nt) {
                    float ig = sigmoidf_(acc[ti][nt].x + bias[ti][0]);
                    float fg = sigmoidf_(acc[ti][nt].y + bias[ti][1]);
                    float gg = tanhf_(acc[ti][nt].z + bias[ti][2]);
                    float og = sigmoidf_(acc[ti][nt].w + bias[ti][3]);
                    cst[ti][nt] = fg * cst[ti][nt] + ig * gg;
                    p[ti][nt] = f2bf(og * tanhf_(cst[ti][nt]));
                }

            // pack u64 per (tile,ntile) combo; lane stores combo == its q
            u64_t myv = 0;
#pragma unroll
            for (int idx = 0; idx < 4; ++idx) {
                const int ti = idx >> 1, nt = idx & 1;
                unsigned a0 = (unsigned)__shfl((int)p[ti][nt], lm);
                unsigned a1 = (unsigned)__shfl((int)p[ti][nt], lm + 16);
                unsigned a2 = (unsigned)__shfl((int)p[ti][nt], lm + 32);
                unsigned a3 = (unsigned)__shfl((int)p[ti][nt], lm + 48);
                u64_t pk = (u64_t)(a0 | (a1 << 16)) | ((u64_t)(a2 | (a3 << 16)) << 32);
                myv = (q == idx) ? pk : myv;
            }
            {
                const int nt = q & 1, ti = q >> 1;
                ushort_t* hdst = hbuf + (size_t)((t + 1) & 1) * (256 * 512);
                g_store64((u64_t*)(hdst + (size_t)(Bg0 + 16 * nt + lm) * 512
                                   + U0 + 8 * mm + 4 * ti), myv);
            }
            asm volatile("s_waitcnt vmcnt(0)" ::: "memory");   // own stores at LLC
            if (lane == 0) g_store_flag(mypub, t + 2);
        }

        // ---- 7. all threads: consume xp -> LDS x_{t+1}; then issue prefetch t+2 ----
        {
            unsigned int* dstx = (unsigned int*)(u_lds + xr * U_STRIDE);
            const bool tz = (tok_cur != 0);
#pragma unroll
            for (int k = 0; k < 10; ++k) {
                int i = xln + 16 * k;
                unsigned int v = 0u;
                if (tz && i < 150)
                    v = (unsigned int)f2bf(xp[k].x) | ((unsigned int)f2bf(xp[k].y) << 16);
                dstx[i] = v;
            }
        }
        {
            tok_cur = tok_nxt;
            const float2* s2 = (const float2*)(emb + (size_t)tok_cur * 300);
#pragma unroll
            for (int k = 0; k < 10; ++k) {
                int i = xln + 16 * k;
                if (i < 150) xp[k] = s2[i];
            }
            int t3 = (t + 3 < 512) ? (t + 3) : 511;
            tok_nxt = tokens[xb * 512 + t3];
        }
        __syncthreads();   // Send: x_{t+1} staged, h region free
    }

    // ---- wait group done (513), then FC: block handles batches Bg0+2*ib, +1 ----
    if (wv == 0) {
        while (true) {
            int v = g_load_flag(myflag);
            if (__all(v >= 513)) break;
            __builtin_amdgcn_s_sleep(1);
        }
        asm volatile("" ::: "memory");
    }
    __syncthreads();

    {
        const int bb = Bg0 + 2 * ib + (wv & 1);
        const int obase = wv >> 1;                       // 0..3
        const ushort_t* hrow = hbuf + (size_t)bb * 512;  // final h in parity 0
        u64_t h0 = g_load64((const u64_t*)(hrow + lane * 8));
        u64_t h1 = g_load64((const u64_t*)(hrow + lane * 8 + 4));
        float hv[8];
#pragma unroll
        for (int j = 0; j < 4; ++j) hv[j]     = bf2f((ushort_t)(h0 >> (16 * j)));
#pragma unroll
        for (int j = 0; j < 4; ++j) hv[4 + j] = bf2f((ushort_t)(h1 >> (16 * j)));
#pragma unroll
        for (int oo = 0; oo < 2; ++oo) {
            int o = obase + oo * 4;
            if (o < 7) {
                f32x4 w0 = *(const f32x4*)(Wfc + o * 512 + lane * 8);
                f32x4 w1 = *(const f32x4*)(Wfc + o * 512 + lane * 8 + 4);
                float s = hv[0] * w0.x + hv[1] * w0.y + hv[2] * w0.z + hv[3] * w0.w
                        + hv[4] * w1.x + hv[5] * w1.y + hv[6] * w1.z + hv[7] * w1.w;
#pragma unroll
                for (int sh = 32; sh >= 1; sh >>= 1) s += __shfl_down(s, sh);
                if (lane == 0)
                    out[bb * 7 + o] = s + bfc[o];
            }
        }
    }
}

extern "C" void kernel_launch(void* const* d_in, const int* in_sizes, int n_in,
                              void* d_out, int out_size, void* d_ws, size_t ws_size,
                              hipStream_t stream) {
    const int* tokens = (const int*)d_in[0];
    const float* emb  = (const float*)d_in[1];
    const float* Wih  = (const float*)d_in[2];
    const float* bih  = (const float*)d_in[3];
    const float* Whh  = (const float*)d_in[4];
    const float* bhh  = (const float*)d_in[5];
    const float* Wfc  = (const float*)d_in[6];
    const float* bfc  = (const float*)d_in[7];

    int* flags      = (int*)d_ws;                       // 512 ints: 64 flags per group
    ushort_t* hbuf  = (ushort_t*)((char*)d_ws + 4096);  // [2][256][512] bf16 = 512 KiB

    lstm_fused_kernel<<<dim3(128), dim3(512), 0, stream>>>(
        tokens, emb, Wih, bih, Whh, bhh, Wfc, bfc,
        (float*)d_out, flags, hbuf);
}